// Round 11
// baseline (7917.870 us; speedup 1.0000x reference)
//
#include <hip/hip_runtime.h>

#define Bz 32
#define Tz 512
#define Dz 512
#define Lz 1024
#define Mz 10
#define G4D 2048
#define JT 64               // j per A-tile
#define NKC 4               // K=1024 split in 4 chunks of 256
#define KCH 256
#define KU 128              // u32 k-pairs per chunk
#define NBLKA 128           // 32 jt x 4 kc
#define NBLK (NBLKA + Bz)   // 160
#define FP 32               // ints per flag slot (128B padding)
// ws int-region offsets
#define OFF_FLAGA 0
#define OFF_FLAGH (NBLKA*FP)            // 4096
#define OFF_FLAGC (OFF_FLAGH + Bz*FP)   // 5120
#define OFF_HP    6144                  // hp[256][32] u32
#define OFF_CP    (OFF_HP + 8192)       // cp[256][32] u32
#define OFF_PART  (OFF_CP + 8192)       // part[4][32][1024] u32 (f16-pair)
#define OFF_XW    (OFF_PART + 131072)   // xw floats after this
// k_pre tiles
#define PM 128
#define PN 128
#define PK 32

typedef unsigned long long u64;
typedef _Float16 half2_t __attribute__((ext_vector_type(2)));

#if defined(__has_builtin)
#if __has_builtin(__builtin_amdgcn_fdot2)
#define HAS_FDOT2 1
#endif
#endif

__device__ __forceinline__ float fsig(float x) { return 1.0f / (1.0f + __expf(-x)); }
__device__ __forceinline__ int ld_rlx(const int* p) {
  return __hip_atomic_load(p, __ATOMIC_RELAXED, __HIP_MEMORY_SCOPE_AGENT);
}
__device__ __forceinline__ void st_rlx(int* p, int v) {
  __hip_atomic_store(p, v, __ATOMIC_RELAXED, __HIP_MEMORY_SCOPE_AGENT);
}
__device__ __forceinline__ void st_rlxu(unsigned* p, unsigned v) {
  __hip_atomic_store(p, v, __ATOMIC_RELAXED, __HIP_MEMORY_SCOPE_AGENT);
}
__device__ __forceinline__ u64 ld_rlx64(const u64* p) {
  return __hip_atomic_load(p, __ATOMIC_RELAXED, __HIP_MEMORY_SCOPE_AGENT);
}
__device__ __forceinline__ unsigned pack16(float a, float b) {
  unsigned short la = __builtin_bit_cast(unsigned short, (_Float16)a);
  unsigned short lb = __builtin_bit_cast(unsigned short, (_Float16)b);
  return (unsigned)la | ((unsigned)lb << 16);
}
__device__ __forceinline__ float dot2f(unsigned xu, unsigned wu, float acc) {
  half2_t xh = __builtin_bit_cast(half2_t, xu);
  half2_t wh = __builtin_bit_cast(half2_t, wu);
#ifdef HAS_FDOT2
  return __builtin_amdgcn_fdot2(xh, wh, acc, false);
#else
  return acc + (float)xh[0]*(float)wh[0] + (float)xh[1]*(float)wh[1];
#endif
}
#define VWAIT() asm volatile("s_waitcnt vmcnt(0)" ::: "memory")
#define ACQ()   __builtin_amdgcn_fence(__ATOMIC_ACQUIRE, "agent")

// ---------------- K0 (once): xw[bt][j] = x[bt,:] . W_ih[j,0:512] + b_ih[j] + b_hh[j] ----------------
__global__ __launch_bounds__(256) void k_pre(
    const float* __restrict__ x, const float* __restrict__ W_ih,
    const float* __restrict__ b_ih, const float* __restrict__ b_hh,
    float* __restrict__ xw)
{
  __shared__ float As[PM][PK+1];
  __shared__ float Bs[PN][PK+1];
  const int m0 = blockIdx.x*PM, n0 = blockIdx.y*PN;
  const int tid = threadIdx.x;
  const int mg = tid >> 4, ng = tid & 15;
  float acc[8][8] = {};
  for (int k0 = 0; k0 < Dz; k0 += PK) {
    for (int i = tid; i < PM*(PK/4); i += 256) {
      int row = i >> 3, c4 = (i & 7) << 2;
      float4 v = *reinterpret_cast<const float4*>(&x[(size_t)(m0+row)*Dz + k0 + c4]);
      As[row][c4] = v.x; As[row][c4+1] = v.y; As[row][c4+2] = v.z; As[row][c4+3] = v.w;
    }
    for (int i = tid; i < PN*(PK/4); i += 256) {
      int row = i >> 3, c4 = (i & 7) << 2;
      float4 v = *reinterpret_cast<const float4*>(&W_ih[(size_t)(n0+row)*(2*Dz) + k0 + c4]);
      Bs[row][c4] = v.x; Bs[row][c4+1] = v.y; Bs[row][c4+2] = v.z; Bs[row][c4+3] = v.w;
    }
    __syncthreads();
    #pragma unroll 8
    for (int k = 0; k < PK; k++) {
      float a8[8], b8[8];
      #pragma unroll
      for (int r = 0; r < 8; r++) a8[r] = As[mg*8+r][k];
      #pragma unroll
      for (int s = 0; s < 8; s++) b8[s] = Bs[ng*8+s][k];
      #pragma unroll
      for (int r = 0; r < 8; r++)
        #pragma unroll
        for (int s = 0; s < 8; s++) acc[r][s] += a8[r]*b8[s];
    }
    __syncthreads();
  }
  #pragma unroll
  for (int r = 0; r < 8; r++) {
    int m = m0 + mg*8 + r;
    #pragma unroll
    for (int s = 0; s < 8; s++) {
      int n = n0 + ng*8 + s;
      xw[(size_t)m*G4D + n] = acc[r][s] + b_ih[n] + b_hh[n];
    }
  }
}

// ---------------- Persistent kernel: f16 payloads; A reads state CACHED after
// an agent-acquire fence (same-XCD A-blocks share the slice via L2) ----------------
__global__ __launch_bounds__(512, 1) void k_persist(
    const float* __restrict__ memory, const int* __restrict__ lens,
    const float* __restrict__ W_ih, const float* __restrict__ W_hh,
    const float* __restrict__ W_g,  const float* __restrict__ b_g,
    const float* __restrict__ xw,
    unsigned* __restrict__ hp, unsigned* __restrict__ cp,
    unsigned* __restrict__ part,
    int* __restrict__ flagA, int* __restrict__ flagH, int* __restrict__ flagC,
    float* __restrict__ ctx_out, float* __restrict__ align_out,
    float* __restrict__ term_out)
{
  const int blk = blockIdx.x, tid = threadIdx.x;

  __shared__ __align__(16) char smem[50304];
  __shared__ float phis[3*Mz], prm[3*Mz];
  __shared__ float lom[Mz], him[Mz];
  __shared__ int   rng[2];

  if (blk < NBLKA) {
    // ================= A role =================
    const int jt = blk >> 2, kc = blk & 3;   // note: kc == (blk%8)&3 -> per-XCD slice sharing
    const int j0 = jt * JT;
    u64 (*Ws2)[131] = reinterpret_cast<u64(*)[131]>(smem);           // [32][131]
    u64 (*Xs2)[131] = reinterpret_cast<u64(*)[131]>(smem + 33536);   // [16][131]

    // stage W tile once: Ws2[jp][ku] = {f16 pair row 2jp, f16 pair row 2jp+1}
    for (int i = tid; i < 32*KU; i += 512) {
      int jp = i >> 7, ku = i & (KU-1);
      int j = j0 + 2*jp;
      int k = kc*KCH + 2*ku;         // k in [0,1024): [0,512)=ctx, [512,1024)=h
      const float *r0, *r1;
      if (k < 512) { r0 = &W_ih[(size_t)j*(2*Dz) + 512 + k]; r1 = r0 + 2*Dz; }
      else         { r0 = &W_hh[(size_t)j*Dz + (k - 512)];   r1 = r0 + Dz; }
      float2 a = *reinterpret_cast<const float2*>(r0);
      float2 b2 = *reinterpret_cast<const float2*>(r1);
      Ws2[jp][ku] = (u64)pack16(a.x, a.y) | ((u64)pack16(b2.x, b2.y) << 32);
    }

    const unsigned* src = (kc < 2) ? cp : hp;
    const int kub = (kc & 1) * KU;
    const int* wf = (kc >= 2) ? flagH : flagC;

    for (int t = 0; t < Tz; ++t) {
      if (t > 0) {
        if (tid < Bz) {
          while (ld_rlx(&wf[tid*FP]) < t) __builtin_amdgcn_s_sleep(1);
        }
        __syncthreads();
        if (tid == 0) ACQ();         // invalidate L1/L2 -> cached reads fresh
        __syncthreads();
      }

      // stage Xs2[bp][ku] from publish arrays — PLAIN cached loads (L2-shared per XCD)
      {
        u64 v[4];
        #pragma unroll
        for (int q = 0; q < 4; q++) {
          int i = (q << 9) + tid;               // 0..2047
          int bp = i >> 7, ku = i & (KU-1);
          v[q] = *reinterpret_cast<const u64*>(src + (size_t)(kub + ku)*Bz + 2*bp);
        }
        #pragma unroll
        for (int q = 0; q < 4; q++) {
          int i = (q << 9) + tid;
          int bp = i >> 7, ku = i & (KU-1);
          Xs2[bp][ku] = v[q];
        }
      }
      __syncthreads();

      // compute: thread owns 2 j x 2 b, 256 k (128 u64 iters, 4 dot2 each)
      {
        const int jp = tid & 31, bp = tid >> 5;
        float a00 = 0.f, a01 = 0.f, a10 = 0.f, a11 = 0.f;
        #pragma unroll 8
        for (int ku = 0; ku < KU; ku++) {
          u64 w = Ws2[jp][ku];
          u64 xv = Xs2[bp][ku];
          unsigned wlo = (unsigned)w,  whi = (unsigned)(w >> 32);
          unsigned xlo = (unsigned)xv, xhi = (unsigned)(xv >> 32);
          a00 = dot2f(xlo, wlo, a00);   // j0,b0
          a10 = dot2f(xlo, whi, a10);   // j1,b0
          a01 = dot2f(xhi, wlo, a01);   // j0,b1
          a11 = dot2f(xhi, whi, a11);   // j1,b1
        }
        const int ju = jt*32 + jp;
        st_rlxu(part + ((size_t)(kc*Bz + 2*bp)    *1024) + ju, pack16(a00, a10));
        st_rlxu(part + ((size_t)(kc*Bz + 2*bp + 1)*1024) + ju, pack16(a01, a11));
      }
      VWAIT();
      __syncthreads();
      if (tid == 0) st_rlx(&flagA[blk*FP], t+1);
    }
    return;
  }

  // ================= B role (no fence: keeps own L2 locality for einsum/xw) =================
  const int b = blk - NBLKA;
  float* gs   = reinterpret_cast<float*>(smem);           // 2048 f (8 KB)
  float* wsm  = reinterpret_cast<float*>(smem + 8192);    // 1024 f
  float* hs   = reinterpret_cast<float*>(smem + 12288);   // 512 f
  float* cs   = reinterpret_cast<float*>(smem + 14336);   // 512 f
  float* ctxl = reinterpret_cast<float*>(smem + 16384);   // 512 f
  unsigned* wgp = reinterpret_cast<unsigned*>(smem + 18432); // 30*256 u32 (30 KB) f16 W_g
  unsigned* hl  = reinterpret_cast<unsigned*>(smem + 49152); // 256 u32 packed h
  float (*part4)[Dz] = reinterpret_cast<float(*)[Dz]>(smem);  // einsum partials overlay gs

  cs[tid] = 0.f;
  // stage W_g as f16 pairs in LDS once (immune to A's L2 invalidates)
  for (int i = tid; i < 3*Mz*256; i += 512) {
    int m = i >> 8, ku = i & 255;
    float2 wv = *reinterpret_cast<const float2*>(&W_g[(size_t)m*Dz + 2*ku]);
    wgp[i] = pack16(wv.x, wv.y);
  }
  __syncthreads();

  for (int t = 0; t < Tz; ++t) {
    // prefetch xw row into registers (before any waiting)
    float4 xwv = *reinterpret_cast<const float4*>(&xw[((size_t)b*Tz + t)*G4D + 4*tid]);

    if (tid < NBLKA) {
      while (ld_rlx(&flagA[tid*FP]) < t+1) __builtin_amdgcn_s_sleep(1);
    }
    __syncthreads();

    // gates = xw + 4 f16 partial chunks (sc1 reads from MALL - always fresh)
    {
      float g0 = xwv.x, g1 = xwv.y, g2v = xwv.z, g3 = xwv.w;
      u64 pv[NKC];
      #pragma unroll
      for (int k2 = 0; k2 < NKC; k2++)
        pv[k2] = ld_rlx64(reinterpret_cast<const u64*>(
                     part + ((size_t)(k2*Bz + b)*1024) + 2*tid));
      #pragma unroll
      for (int k2 = 0; k2 < NKC; k2++) {
        half2_t hlv = __builtin_bit_cast(half2_t, (unsigned)pv[k2]);
        half2_t hhv = __builtin_bit_cast(half2_t, (unsigned)(pv[k2] >> 32));
        g0 += (float)hlv[0]; g1 += (float)hlv[1];
        g2v += (float)hhv[0]; g3 += (float)hhv[1];
      }
      *reinterpret_cast<float4*>(&gs[4*tid]) = make_float4(g0, g1, g2v, g3);
    }
    __syncthreads();

    // LSTM pointwise (d = tid), state fp32 in LDS
    {
      const int d = tid;
      float ig = 1.0f/(1.0f+expf(-gs[d]));
      float fg = 1.0f/(1.0f+expf(-gs[Dz+d]));
      float gg = tanhf(gs[2*Dz+d]);
      float og = 1.0f/(1.0f+expf(-gs[3*Dz+d]));
      float cn = fg*cs[d] + ig*gg;
      float hn = og*tanhf(cn);
      cs[d] = cn; hs[d] = hn;
    }
    __syncthreads();
    // publish h as packed f16 (k-major hp[u][b]) + keep local packed copy
    if (tid < 256) {
      unsigned ph = pack16(hs[2*tid], hs[2*tid+1]);
      hl[tid] = ph;
      st_rlxu(&hp[(size_t)tid*Bz + b], ph);
    }
    VWAIT();
    __syncthreads();
    if (tid == 0) st_rlx(&flagH[b*FP], t+1);   // release h-side A-blocks NOW

    // phi[m] = hs . W_g[m,:] + b_g[m]  (16 lanes/m, f16 dot2 from LDS)
    if (tid < 16*3*Mz) {
      int m = tid >> 4, l16 = tid & 15;
      const unsigned* wr = wgp + m*256;
      float s = 0.f;
      #pragma unroll
      for (int i = 0; i < 16; i++) {
        int ku = l16 + (i << 4);
        s = dot2f(hl[ku], wr[ku], s);
      }
      s += __shfl_xor(s, 1);
      s += __shfl_xor(s, 2);
      s += __shfl_xor(s, 4);
      s += __shfl_xor(s, 8);
      if (l16 == 0) phis[m] = s + b_g[m];
    }
    __syncthreads();

    // GMM params
    if (tid < Mz) {
      float ks = expf(phis[tid]);
      float be = expf(phis[Mz + tid]);
      prm[tid]      = ks;
      prm[Mz + tid] = expf(-phis[Mz + tid]);   // 1/beta
      lom[tid] = ks - 0.5f - 25.f*be;          // sig(-25) < fp32 visibility
      him[tid] = ks + 0.5f + 25.f*be;
    }
    __syncthreads();
    if (tid == 0) {
      float mx = -1e30f;
      #pragma unroll
      for (int m = 0; m < Mz; m++) mx = fmaxf(mx, phis[2*Mz + m]);
      float ae[Mz], ssum = 0.f;
      #pragma unroll
      for (int m = 0; m < Mz; m++) { ae[m] = expf(phis[2*Mz + m] - mx); ssum += ae[m]; }
      float lo = 1e30f, hi = -1e30f;
      #pragma unroll
      for (int m = 0; m < Mz; m++) {
        prm[2*Mz + m] = ae[m] / ssum;
        lo = fminf(lo, lom[m]); hi = fmaxf(hi, him[m]);
      }
      int llo = lo > 0.f ? (int)floorf(lo) : 0;
      if (llo > Lz) llo = Lz;
      int lhi = hi < (float)Lz ? (int)ceilf(hi) + 1 : Lz;
      if (lhi > Lz) lhi = Lz;
      rng[0] = llo; rng[1] = lhi;
    }
    __syncthreads();
    const int llo = rng[0], lhi = rng[1];

    // w on active range
    for (int l = llo + tid; l < lhi; l += 512) {
      float u = (float)l;
      float t1 = 0.f, t0 = 0.f;
      #pragma unroll
      for (int m = 0; m < Mz; m++) {
        float ks = prm[m], ib = prm[Mz + m], al = prm[2*Mz + m];
        t1 += al * fsig((u + 0.5f - ks) * ib);
        t0 += al * fsig((u - 0.5f - ks) * ib);
      }
      wsm[l] = t1 - t0;
    }
    __syncthreads();

    // ctx einsum: 4 groups of 128 threads split l-range; lane owns 4 d (float4)
    {
      const int grp = tid >> 7, lane = tid & 127, d0 = lane << 2;
      const float* mb = memory + (size_t)b*Lz*Dz + d0;
      float4 a = make_float4(0.f, 0.f, 0.f, 0.f);
      for (int l = llo + grp; l < lhi; l += 4) {
        float w = wsm[l];
        float4 m0 = *reinterpret_cast<const float4*>(&mb[(size_t)l*Dz]);
        a.x = fmaf(w, m0.x, a.x); a.y = fmaf(w, m0.y, a.y);
        a.z = fmaf(w, m0.z, a.z); a.w = fmaf(w, m0.w, a.w);
      }
      *reinterpret_cast<float4*>(&part4[grp][d0]) = a;
    }
    __syncthreads();
    {
      const int d = tid;
      float s = part4[0][d] + part4[1][d] + part4[2][d] + part4[3][d];
      ctxl[d] = s;
      if (t == Tz-1) ctx_out[b*Dz + d] = s;
    }
    __syncthreads();
    // publish ctx as packed f16, k-major cp[u][b]
    if (tid < 256)
      st_rlxu(&cp[(size_t)tid*Bz + b], pack16(ctxl[2*tid], ctxl[2*tid+1]));
    VWAIT();
    __syncthreads();
    if (tid == 0) st_rlx(&flagC[b*FP], t+1);   // release ctx-side A-blocks

    // off critical path: alignment row + termination
    for (int l = llo + tid; l < lhi; l += 512)
      align_out[((size_t)b*Tz + t)*Lz + l] = wsm[l];
    if (t == Tz-1 && tid == 0) {
      float u = (float)(lens[b] - 1);
      float t1 = 0.f;
      #pragma unroll
      for (int m = 0; m < Mz; m++)
        t1 += prm[2*Mz + m] * fsig((u + 0.5f - prm[m]) * prm[Mz + m]);
      term_out[b] = 1.0f - t1;
    }
  }
}

// ================= fallback (small ws): two-kernel loop path =================
__global__ __launch_bounds__(256) void k_gemm(
    const float* __restrict__ x_all, const float* __restrict__ ctxs,
    const float* __restrict__ h, const float* __restrict__ W_ih,
    const float* __restrict__ W_hh, float* __restrict__ partial, int t)
{
  __shared__ float Xs[Bz][130];
  __shared__ float Wt[128][130];
  const int jt = blockIdx.x, kcb = blockIdx.y;
  const int j0 = jt*128, k0 = kcb*128;
  const int tid = threadIdx.x;
  for (int i = tid; i < Bz*128; i += 256) {
    int bb = i >> 7, kk = i & 127;
    int k = k0 + kk;
    float v;
    if (k < Dz)        v = x_all[((size_t)bb*Tz + t)*Dz + k];
    else if (k < 2*Dz) v = ctxs[bb*Dz + (k - Dz)];
    else               v = h[bb*Dz + (k - 2*Dz)];
    Xs[bb][kk] = v;
  }
  {
    const float* Wsrc; int ldw, col0;
    if (k0 < 2*Dz) { Wsrc = W_ih; ldw = 2*Dz; col0 = k0; }
    else           { Wsrc = W_hh; ldw = Dz;   col0 = k0 - 2*Dz; }
    for (int i = tid; i < 128*32; i += 256) {
      int jj = i >> 5, k4 = (i & 31) << 2;
      float4 v = *reinterpret_cast<const float4*>(&Wsrc[(size_t)(j0 + jj)*ldw + col0 + k4]);
      Wt[jj][k4] = v.x; Wt[jj][k4+1] = v.y; Wt[jj][k4+2] = v.z; Wt[jj][k4+3] = v.w;
    }
  }
  __syncthreads();
  const int jg = tid & 31, bg = tid >> 5;
  const int bl = bg << 2;
  float acc[4][4] = {};
  #pragma unroll 4
  for (int k = 0; k < 128; k += 2) {
    float2 xv[4], wv[4];
    #pragma unroll
    for (int b2 = 0; b2 < 4; b2++)
      xv[b2] = *reinterpret_cast<const float2*>(&Xs[bl + b2][k]);
    #pragma unroll
    for (int jj = 0; jj < 4; jj++)
      wv[jj] = *reinterpret_cast<const float2*>(&Wt[jg + (jj << 5)][k]);
    #pragma unroll
    for (int jj = 0; jj < 4; jj++)
      #pragma unroll
      for (int b2 = 0; b2 < 4; b2++)
        acc[jj][b2] += wv[jj].x * xv[b2].x + wv[jj].y * xv[b2].y;
  }
  #pragma unroll
  for (int jj = 0; jj < 4; jj++)
    #pragma unroll
    for (int b2 = 0; b2 < 4; b2++)
      partial[((size_t)kcb*Bz + (bl + b2))*G4D + j0 + jg + (jj << 5)] = acc[jj][b2];
}

__global__ __launch_bounds__(512) void k_fused(
    const float* __restrict__ partial, const float* __restrict__ b_ih,
    const float* __restrict__ b_hh,
    float* __restrict__ h, float* __restrict__ c,
    const float* __restrict__ W_g, const float* __restrict__ b_g,
    const float* __restrict__ memory, const int* __restrict__ lens,
    float* __restrict__ ctxs, float* __restrict__ ctx_out,
    float* __restrict__ align_out, float* __restrict__ term_out,
    int t, int final_, int nkc)
{
  const int b = blockIdx.x, tid = threadIdx.x;
  __shared__ float4 gs4[G4D/4];
  __shared__ float hsb[Dz];
  __shared__ float phis[3*Mz];
  __shared__ float prm[3*Mz];
  __shared__ float wsm[Lz];
  __shared__ int   rng[2];
  float* gs = (float*)gs4;
  {
    int j = 4*tid;
    float4 bi = *reinterpret_cast<const float4*>(&b_ih[j]);
    float4 bh = *reinterpret_cast<const float4*>(&b_hh[j]);
    float4 s = make_float4(bi.x+bh.x, bi.y+bh.y, bi.z+bh.z, bi.w+bh.w);
    const float4* pp = reinterpret_cast<const float4*>(partial) + (size_t)b*(G4D/4) + tid;
    for (int kcb = 0; kcb < nkc; kcb++) {
      float4 p = pp[(size_t)kcb*Bz*(G4D/4)];
      s.x += p.x; s.y += p.y; s.z += p.z; s.w += p.w;
    }
    gs4[tid] = s;
  }
  __syncthreads();
  {
    const int d = tid;
    float ig = 1.0f / (1.0f + expf(-gs[d]));
    float fg = 1.0f / (1.0f + expf(-gs[Dz + d]));
    float gg = tanhf(gs[2*Dz + d]);
    float og = 1.0f / (1.0f + expf(-gs[3*Dz + d]));
    float cn = fg * c[b*Dz + d] + ig * gg;
    float hn = og * tanhf(cn);
    c[b*Dz + d] = cn;
    h[b*Dz + d] = hn;
    hsb[d] = hn;
  }
  __syncthreads();
  if (tid < 16*3*Mz) {
    int m = tid >> 4, l16 = tid & 15;
    float s = 0.f;
    #pragma unroll 4
    for (int k = l16; k < Dz; k += 16) s += W_g[m*Dz + k] * hsb[k];
    s += __shfl_xor(s, 1);
    s += __shfl_xor(s, 2);
    s += __shfl_xor(s, 4);
    s += __shfl_xor(s, 8);
    if (l16 == 0) phis[m] = s + b_g[m];
  }
  __syncthreads();
  if (tid == 0) {
    float mx = -1e30f;
    #pragma unroll
    for (int m = 0; m < Mz; m++) mx = fmaxf(mx, phis[2*Mz + m]);
    float ae[Mz], ssum = 0.f;
    #pragma unroll
    for (int m = 0; m < Mz; m++) { ae[m] = expf(phis[2*Mz + m] - mx); ssum += ae[m]; }
    float lo = 1e30f, hi = -1e30f;
    #pragma unroll
    for (int m = 0; m < Mz; m++) {
      float ks = expf(phis[m]);
      float be = expf(phis[Mz + m]);
      prm[m]        = ks;
      prm[Mz + m]   = expf(-phis[Mz + m]);
      prm[2*Mz + m] = ae[m] / ssum;
      lo = fminf(lo, ks - 0.5f - 25.f*be);
      hi = fmaxf(hi, ks + 0.5f + 25.f*be);
    }
    int llo = lo > 0.f ? (int)floorf(lo) : 0;
    if (llo > Lz) llo = Lz;
    int lhi = hi < (float)Lz ? (int)ceilf(hi) + 1 : Lz;
    if (lhi > Lz) lhi = Lz;
    rng[0] = llo; rng[1] = lhi;
  }
  __syncthreads();
  const int llo = rng[0], lhi = rng[1];
  for (int l = llo + tid; l < lhi; l += 512) {
    float u = (float)l;
    float t1 = 0.f, t0 = 0.f;
    #pragma unroll
    for (int m = 0; m < Mz; m++) {
      float ks = prm[m], ib = prm[Mz + m], al = prm[2*Mz + m];
      t1 += al * fsig((u + 0.5f - ks) * ib);
      t0 += al * fsig((u - 0.5f - ks) * ib);
    }
    float w = t1 - t0;
    wsm[l] = w;
    align_out[((size_t)b*Tz + t)*Lz + l] = w;
  }
  __syncthreads();
  {
    const float* mb = memory + (size_t)b*Lz*Dz + tid;
    float acc = 0.f;
    #pragma unroll 4
    for (int l = llo; l < lhi; l++)
      acc += wsm[l] * mb[(size_t)l*Dz];
    ctxs[b*Dz + tid] = acc;
    if (final_) ctx_out[b*Dz + tid] = acc;
  }
  if (final_ && tid == 0) {
    float u = (float)(lens[b] - 1);
    float t1 = 0.f;
    #pragma unroll
    for (int m = 0; m < Mz; m++)
      t1 += prm[2*Mz + m] * fsig((u + 0.5f - prm[m]) * prm[Mz + m]);
    term_out[b] = 1.0f - t1;
  }
}

extern "C" void kernel_launch(void* const* d_in, const int* in_sizes, int n_in,
                              void* d_out, int out_size, void* d_ws, size_t ws_size,
                              hipStream_t stream)
{
  (void)in_sizes; (void)n_in; (void)out_size;
  const float* x    = (const float*)d_in[0];
  const float* mem  = (const float*)d_in[1];
  const int*   lens = (const int*)d_in[2];
  const float* W_ih = (const float*)d_in[3];
  const float* W_hh = (const float*)d_in[4];
  const float* b_ih = (const float*)d_in[5];
  const float* b_hh = (const float*)d_in[6];
  const float* W_g  = (const float*)d_in[7];
  const float* b_g  = (const float*)d_in[8];

  float* out = (float*)d_out;
  float* ctx_out   = out;                                  // [B,1,D]
  float* align_out = out + Bz*Dz;                          // [B,T,L]
  float* term_out  = out + Bz*Dz + (size_t)Bz*Tz*Lz;       // [B,1]

  const size_t needP = (size_t)OFF_XW*4 + (size_t)Bz*Tz*G4D*sizeof(float);

  hipMemsetAsync(align_out, 0, (size_t)Bz*Tz*Lz*sizeof(float), stream);

  if (ws_size >= needP) {
    int*      ip    = (int*)d_ws;
    int*      flagA = ip + OFF_FLAGA;
    int*      flagH = ip + OFF_FLAGH;
    int*      flagC = ip + OFF_FLAGC;
    unsigned* hp    = (unsigned*)(ip + OFF_HP);
    unsigned* cp    = (unsigned*)(ip + OFF_CP);
    unsigned* part  = (unsigned*)(ip + OFF_PART);
    float*    xw    = (float*)(ip + OFF_XW);

    // zero flags + hp + cp (initial state = 0)
    hipMemsetAsync(d_ws, 0, (size_t)OFF_PART*4, stream);
    k_pre<<<dim3((Bz*Tz)/PM, G4D/PN), 256, 0, stream>>>(x, W_ih, b_ih, b_hh, xw);
    k_persist<<<NBLK, 512, 0, stream>>>(mem, lens, W_ih, W_hh, W_g, b_g, xw,
                                        hp, cp, part, flagA, flagH, flagC,
                                        ctx_out, align_out, term_out);
  } else {
    float* wsf     = (float*)d_ws;
    float* h       = wsf;
    float* c       = h + Bz*Dz;
    float* ctxs    = c + Bz*Dz;
    float* partial = ctxs + Bz*Dz;               // [12][B][4D]
    hipMemsetAsync(d_ws, 0, (size_t)(3*Bz*Dz)*sizeof(float), stream);
    for (int t = 0; t < Tz; t++) {
      k_gemm<<<dim3(G4D/128, 12), 256, 0, stream>>>(x, ctxs, h, W_ih, W_hh, partial, t);
      k_fused<<<Bz, 512, 0, stream>>>(partial, b_ih, b_hh, h, c, W_g, b_g,
                                      mem, lens, ctxs, ctx_out, align_out, term_out,
                                      t, t == Tz-1, 12);
    }
  }
}

// Round 13
// 6793.790 us; speedup vs baseline: 1.1655x; 1.1655x over previous
//
#include <hip/hip_runtime.h>

#define Bz 32
#define Tz 512
#define Dz 512
#define Lz 1024
#define Mz 10
#define G4D 2048
#define FP 32               // ints per flag slot (128B)
#define NBLKA 32            // 16 j-slices x 2 K-halves
#define NBLK 64             // + 32 B-blocks
// ws int-region offsets
#define OFF_FG   0                       // [32*FP]
#define OFF_FH   1024                    // [32*FP]
#define OFF_FC   2048                    // [32*FP]
#define OFF_SC   3072                    // stat_c[32][256] u32 (b-major f16 pairs)
#define OFF_SH   11264                   // stat_h[32][256] u32
#define OFF_PART 19456                   // part[2][32][1024] u32 (f16 pairs)
#define OFF_XW   84992                   // xw floats
// k_pre tiles
#define PM 128
#define PN 128
#define PK 32

typedef unsigned long long u64;
typedef unsigned u32;
typedef _Float16 f16x8 __attribute__((ext_vector_type(8)));
typedef float f32x4 __attribute__((ext_vector_type(4)));
typedef _Float16 half2_t __attribute__((ext_vector_type(2)));

__device__ __forceinline__ float fsig(float x) { return 1.0f / (1.0f + __expf(-x)); }
__device__ __forceinline__ int ld_rlx(const int* p) {
  return __hip_atomic_load(p, __ATOMIC_RELAXED, __HIP_MEMORY_SCOPE_AGENT);
}
__device__ __forceinline__ void st_rlx(int* p, int v) {
  __hip_atomic_store(p, v, __ATOMIC_RELAXED, __HIP_MEMORY_SCOPE_AGENT);
}
__device__ __forceinline__ void st_rlxu(u32* p, u32 v) {
  __hip_atomic_store(p, v, __ATOMIC_RELAXED, __HIP_MEMORY_SCOPE_AGENT);
}
__device__ __forceinline__ u64 ld_rlx64(const u64* p) {
  return __hip_atomic_load(p, __ATOMIC_RELAXED, __HIP_MEMORY_SCOPE_AGENT);
}
__device__ __forceinline__ u32 pack16(float a, float b) {
  unsigned short la = __builtin_bit_cast(unsigned short, (_Float16)a);
  unsigned short lb = __builtin_bit_cast(unsigned short, (_Float16)b);
  return (u32)la | ((u32)lb << 16);
}
#define VWAIT() asm volatile("s_waitcnt vmcnt(0)" ::: "memory")

// ---------------- K0 (once): xw[bt][j] = x[bt,:] . W_ih[j,0:512] + b_ih[j] + b_hh[j] ----------------
__global__ __launch_bounds__(256) void k_pre(
    const float* __restrict__ x, const float* __restrict__ W_ih,
    const float* __restrict__ b_ih, const float* __restrict__ b_hh,
    float* __restrict__ xw)
{
  __shared__ float As[PM][PK+1];
  __shared__ float Bs[PN][PK+1];
  const int m0 = blockIdx.x*PM, n0 = blockIdx.y*PN;
  const int tid = threadIdx.x;
  const int mg = tid >> 4, ng = tid & 15;
  float acc[8][8] = {};
  for (int k0 = 0; k0 < Dz; k0 += PK) {
    for (int i = tid; i < PM*(PK/4); i += 256) {
      int row = i >> 3, c4 = (i & 7) << 2;
      float4 v = *reinterpret_cast<const float4*>(&x[(size_t)(m0+row)*Dz + k0 + c4]);
      As[row][c4] = v.x; As[row][c4+1] = v.y; As[row][c4+2] = v.z; As[row][c4+3] = v.w;
    }
    for (int i = tid; i < PN*(PK/4); i += 256) {
      int row = i >> 3, c4 = (i & 7) << 2;
      float4 v = *reinterpret_cast<const float4*>(&W_ih[(size_t)(n0+row)*(2*Dz) + k0 + c4]);
      Bs[row][c4] = v.x; Bs[row][c4+1] = v.y; Bs[row][c4+2] = v.z; Bs[row][c4+3] = v.w;
    }
    __syncthreads();
    #pragma unroll 8
    for (int k = 0; k < PK; k++) {
      float a8[8], b8[8];
      #pragma unroll
      for (int r = 0; r < 8; r++) a8[r] = As[mg*8+r][k];
      #pragma unroll
      for (int s = 0; s < 8; s++) b8[s] = Bs[ng*8+s][k];
      #pragma unroll
      for (int r = 0; r < 8; r++)
        #pragma unroll
        for (int s = 0; s < 8; s++) acc[r][s] += a8[r]*b8[s];
    }
    __syncthreads();
  }
  #pragma unroll
  for (int r = 0; r < 8; r++) {
    int m = m0 + mg*8 + r;
    #pragma unroll
    for (int s = 0; s < 8; s++) {
      int n = n0 + ng*8 + s;
      xw[(size_t)m*G4D + n] = acc[r][s] + b_ih[n] + b_hh[n];
    }
  }
}

// ---------------- Persistent kernel: MFMA gates GEMM + sc1/MALL exchange ----------------
// A blocks 0..31: jt = blk>>1 (128 j each), kc = blk&1 (0=ctx K-half, 1=h K-half).
//   W f16 in LDS [128][260] u32; state staged in 2 sub-halves of 16 batches.
//   Gates computed with v_mfma_f32_16x16x32_f16 (M=16 batches, N=16 j, K=32).
// B blocks 32..63: per-batch reduce(2 chunks)+LSTM+GMM+attention; publishes
//   h/ctx as b-major packed-f16 stat arrays.
__global__ __launch_bounds__(512, 1) void k_persist(
    const float* __restrict__ memory, const int* __restrict__ lens,
    const float* __restrict__ W_ih, const float* __restrict__ W_hh,
    const float* __restrict__ W_g,  const float* __restrict__ b_g,
    const float* __restrict__ xw,
    u32* __restrict__ stat_c, u32* __restrict__ stat_h, u32* __restrict__ part,
    int* __restrict__ fG, int* __restrict__ fH, int* __restrict__ fC,
    float* __restrict__ ctx_out, float* __restrict__ align_out,
    float* __restrict__ term_out)
{
  const int blk = blockIdx.x, tid = threadIdx.x;
  __shared__ __align__(16) char smem[149760];
  __shared__ float phis[3*Mz], prm[3*Mz], lom[Mz], him[Mz];
  __shared__ int rng[2];

  if (blk < NBLKA) {
    // ================= A role =================
    const int jt = blk >> 1, kc = blk & 1;
    const int j0 = jt * 128;
    u32* Wl = (u32*)smem;                 // [128][260] f16-pair rows, 16B-aligned rows
    u32* xs = (u32*)(smem + 133120);      // [16][260]

    // stage W slice once: Wl[jl][ku] = pack(W[j0+jl][2ku], W[j0+jl][2ku+1])
    for (int i = tid; i < 128*256; i += 512) {
      int jl = i >> 8, ku = i & 255;
      int k = 2*ku;
      float2 wv;
      if (kc == 0) wv = *reinterpret_cast<const float2*>(&W_ih[(size_t)(j0+jl)*(2*Dz) + 512 + k]);
      else         wv = *reinterpret_cast<const float2*>(&W_hh[(size_t)(j0+jl)*Dz + k]);
      Wl[jl*260 + ku] = pack16(wv.x, wv.y);
    }

    const u32* statS = (kc == 0) ? stat_c : stat_h;
    const int* wf    = (kc == 0) ? fC : fH;
    const int w = tid >> 6, lane = tid & 63;
    const int fr = lane & 15;             // fragment 16-index (batch row / j col)
    const int kq = (lane >> 4) << 2;      // k-offset of frag in u32 units (8 f16)

    for (int t = 0; t < Tz; ++t) {
      if (t > 0 && tid < Bz) {
        while (ld_rlx(&wf[tid*FP]) < t) __builtin_amdgcn_s_sleep(1);
      }
      __syncthreads();     // also covers W staging at t=0

      #pragma unroll
      for (int h = 0; h < 2; ++h) {
        // stage 16 batches' K-half (b-major stat, identity u64 copy)
        #pragma unroll
        for (int q = 0; q < 4; ++q) {
          int flat = (q << 9) + tid;          // 0..2047
          int bb = flat >> 7, ku2 = flat & 127;
          u64 v = ld_rlx64(reinterpret_cast<const u64*>(statS) + (size_t)(h*16 + bb)*128 + ku2);
          *reinterpret_cast<u64*>(&xs[bb*260 + 2*ku2]) = v;
        }
        __syncthreads();

        // MFMA: wave w owns j-tile w (16 j), all 16 batches of this half, K=512
        f32x4 acc = {0.f, 0.f, 0.f, 0.f};
        const u32* ar = xs + fr*260 + kq;
        const u32* br = Wl + (w*16 + fr)*260 + kq;
        #pragma unroll
        for (int ks = 0; ks < 16; ++ks) {
          f16x8 av = *reinterpret_cast<const f16x8*>(ar + ks*16);
          f16x8 bv = *reinterpret_cast<const f16x8*>(br + ks*16);
          acc = __builtin_amdgcn_mfma_f32_16x16x32_f16(av, bv, acc, 0, 0, 0);
        }
        // D: row=(lane>>4)*4+i (batch), col=lane&15 (j). Pack j-pairs via lane^1.
        #pragma unroll
        for (int i = 0; i < 4; ++i) {
          float oth = __shfl_xor(acc[i], 1);
          if (!(lane & 1)) {
            int bg = h*16 + ((lane >> 4) << 2) + i;
            int jc = j0 + w*16 + fr;
            st_rlxu(&part[kc*(Bz*1024) + bg*1024 + (jc >> 1)], pack16(acc[i], oth));
          }
        }
        __syncthreads();   // protect xs before restaging next half
      }
      VWAIT();
      __syncthreads();
      if (tid == 0) st_rlx(&fG[blk*FP], t+1);
    }
    return;
  }

  // ================= B role =================
  const int b = blk - NBLKA;
  float* gs   = reinterpret_cast<float*>(smem);           // 2048 f
  float* wsm  = reinterpret_cast<float*>(smem + 8192);    // 1024 f
  float* hs   = reinterpret_cast<float*>(smem + 12288);   // 512 f
  float* cs   = reinterpret_cast<float*>(smem + 14336);   // 512 f
  float* ctxl = reinterpret_cast<float*>(smem + 16384);   // 512 f
  float* part4 = gs;                                      // einsum partials overlay gs

  cs[tid] = 0.f;
  __syncthreads();

  for (int t = 0; t < Tz; ++t) {
    // prefetch xw row before waiting
    float4 xwv = *reinterpret_cast<const float4*>(&xw[((size_t)b*Tz + t)*G4D + 4*tid]);

    if (tid < NBLKA) {
      while (ld_rlx(&fG[tid*FP]) < t+1) __builtin_amdgcn_s_sleep(1);
    }
    __syncthreads();

    // gates = xw + 2 f16 partial chunks; thread owns j = 4tid..4tid+3
    {
      u64 p0 = ld_rlx64(reinterpret_cast<const u64*>(part) + (size_t)(0*Bz + b)*512 + tid);
      u64 p1 = ld_rlx64(reinterpret_cast<const u64*>(part) + (size_t)(1*Bz + b)*512 + tid);
      float g0 = xwv.x, g1 = xwv.y, g2v = xwv.z, g3 = xwv.w;
      half2_t l0 = __builtin_bit_cast(half2_t, (u32)p0);
      half2_t h0 = __builtin_bit_cast(half2_t, (u32)(p0 >> 32));
      half2_t l1 = __builtin_bit_cast(half2_t, (u32)p1);
      half2_t h1 = __builtin_bit_cast(half2_t, (u32)(p1 >> 32));
      g0 += (float)l0[0] + (float)l1[0];
      g1 += (float)l0[1] + (float)l1[1];
      g2v += (float)h0[0] + (float)h1[0];
      g3 += (float)h0[1] + (float)h1[1];
      *reinterpret_cast<float4*>(&gs[4*tid]) = make_float4(g0, g1, g2v, g3);
    }
    __syncthreads();

    // LSTM pointwise (d = tid), state fp32 in LDS; gate order i,f,g,o
    {
      const int d = tid;
      float ig = 1.0f/(1.0f+expf(-gs[d]));
      float fg = 1.0f/(1.0f+expf(-gs[Dz+d]));
      float gg = tanhf(gs[2*Dz+d]);
      float og = 1.0f/(1.0f+expf(-gs[3*Dz+d]));
      float cn = fg*cs[d] + ig*gg;
      float hn = og*tanhf(cn);
      cs[d] = cn; hs[d] = hn;
    }
    __syncthreads();
    // publish h (b-major packed f16)
    if (tid < 256)
      st_rlxu(&stat_h[b*256 + tid], pack16(hs[2*tid], hs[2*tid+1]));
    VWAIT();
    __syncthreads();
    if (tid == 0) st_rlx(&fH[b*FP], t+1);   // release h-side A-blocks NOW

    // phi[m] = hs . W_g[m,:] + b_g[m]  (16 lanes/m, float4 rows)
    if (tid < 16*3*Mz) {
      int m = tid >> 4, l16 = tid & 15;
      const float4* wr = reinterpret_cast<const float4*>(W_g + m*Dz);
      const float4* hr = reinterpret_cast<const float4*>(hs);
      float s = 0.f;
      #pragma unroll
      for (int i = 0; i < 8; i++) {
        float4 wv = wr[l16 + (i<<4)];
        float4 hv = hr[l16 + (i<<4)];
        s += wv.x*hv.x + wv.y*hv.y + wv.z*hv.z + wv.w*hv.w;
      }
      s += __shfl_xor(s, 1);
      s += __shfl_xor(s, 2);
      s += __shfl_xor(s, 4);
      s += __shfl_xor(s, 8);
      if (l16 == 0) phis[m] = s + b_g[m];
    }
    __syncthreads();

    // GMM params + active range
    if (tid < Mz) {
      float ks = expf(phis[tid]);
      float be = expf(phis[Mz + tid]);
      prm[tid]      = ks;
      prm[Mz + tid] = expf(-phis[Mz + tid]);   // 1/beta
      lom[tid] = ks - 0.5f - 25.f*be;          // sig(-25) < fp32 visibility
      him[tid] = ks + 0.5f + 25.f*be;
    }
    __syncthreads();
    if (tid == 0) {
      float mx = -1e30f;
      #pragma unroll
      for (int m = 0; m < Mz; m++) mx = fmaxf(mx, phis[2*Mz + m]);
      float ae[Mz], ssum = 0.f;
      #pragma unroll
      for (int m = 0; m < Mz; m++) { ae[m] = expf(phis[2*Mz + m] - mx); ssum += ae[m]; }
      float lo = 1e30f, hi = -1e30f;
      #pragma unroll
      for (int m = 0; m < Mz; m++) {
        prm[2*Mz + m] = ae[m] / ssum;
        lo = fminf(lo, lom[m]); hi = fmaxf(hi, him[m]);
      }
      int llo = lo > 0.f ? (int)floorf(lo) : 0;
      if (llo > Lz) llo = Lz;
      int lhi = hi < (float)Lz ? (int)ceilf(hi) + 1 : Lz;
      if (lhi > Lz) lhi = Lz;
      rng[0] = llo; rng[1] = lhi;
    }
    __syncthreads();
    const int llo = rng[0], lhi = rng[1];

    // w on active range
    for (int l = llo + tid; l < lhi; l += 512) {
      float u = (float)l;
      float t1 = 0.f, t0 = 0.f;
      #pragma unroll
      for (int m = 0; m < Mz; m++) {
        float ks = prm[m], ib = prm[Mz + m], al = prm[2*Mz + m];
        t1 += al * fsig((u + 0.5f - ks) * ib);
        t0 += al * fsig((u - 0.5f - ks) * ib);
      }
      wsm[l] = t1 - t0;
    }
    __syncthreads();

    // ctx einsum: 4 groups of 128 threads split l-range; lane owns 4 d (float4)
    {
      const int grp = tid >> 7, d0 = (tid & 127) << 2;
      const float* mb = memory + (size_t)b*Lz*Dz + d0;
      float4 a = make_float4(0.f, 0.f, 0.f, 0.f);
      for (int l = llo + grp; l < lhi; l += 4) {
        float w2 = wsm[l];
        float4 m0 = *reinterpret_cast<const float4*>(&mb[(size_t)l*Dz]);
        a.x = fmaf(w2, m0.x, a.x); a.y = fmaf(w2, m0.y, a.y);
        a.z = fmaf(w2, m0.z, a.z); a.w = fmaf(w2, m0.w, a.w);
      }
      *reinterpret_cast<float4*>(&part4[grp*512 + d0]) = a;
    }
    __syncthreads();
    {
      const int d = tid;
      float s = part4[d] + part4[512 + d] + part4[1024 + d] + part4[1536 + d];
      ctxl[d] = s;
      if (t == Tz-1) ctx_out[b*Dz + d] = s;
    }
    __syncthreads();
    // publish ctx (b-major packed f16)
    if (tid < 256)
      st_rlxu(&stat_c[b*256 + tid], pack16(ctxl[2*tid], ctxl[2*tid+1]));
    VWAIT();
    __syncthreads();
    if (tid == 0) st_rlx(&fC[b*FP], t+1);   // release ctx-side A-blocks

    // off critical path: alignment row + termination
    for (int l = llo + tid; l < lhi; l += 512)
      align_out[((size_t)b*Tz + t)*Lz + l] = wsm[l];
    if (t == Tz-1 && tid == 0) {
      float u = (float)(lens[b] - 1);
      float t1 = 0.f;
      #pragma unroll
      for (int m = 0; m < Mz; m++)
        t1 += prm[2*Mz + m] * fsig((u + 0.5f - prm[m]) * prm[Mz + m]);
      term_out[b] = 1.0f - t1;
    }
  }
}

// ================= fallback (small ws): two-kernel loop path =================
__global__ __launch_bounds__(256) void k_gemm(
    const float* __restrict__ x_all, const float* __restrict__ ctxs,
    const float* __restrict__ h, const float* __restrict__ W_ih,
    const float* __restrict__ W_hh, float* __restrict__ partial, int t)
{
  __shared__ float Xs[Bz][130];
  __shared__ float Wt[128][130];
  const int jt = blockIdx.x, kcb = blockIdx.y;
  const int j0 = jt*128, k0 = kcb*128;
  const int tid = threadIdx.x;
  for (int i = tid; i < Bz*128; i += 256) {
    int bb = i >> 7, kk = i & 127;
    int k = k0 + kk;
    float v;
    if (k < Dz)        v = x_all[((size_t)bb*Tz + t)*Dz + k];
    else if (k < 2*Dz) v = ctxs[bb*Dz + (k - Dz)];
    else               v = h[bb*Dz + (k - 2*Dz)];
    Xs[bb][kk] = v;
  }
  {
    const float* Wsrc; int ldw, col0;
    if (k0 < 2*Dz) { Wsrc = W_ih; ldw = 2*Dz; col0 = k0; }
    else           { Wsrc = W_hh; ldw = Dz;   col0 = k0 - 2*Dz; }
    for (int i = tid; i < 128*32; i += 256) {
      int jj = i >> 5, k4 = (i & 31) << 2;
      float4 v = *reinterpret_cast<const float4*>(&Wsrc[(size_t)(j0 + jj)*ldw + col0 + k4]);
      Wt[jj][k4] = v.x; Wt[jj][k4+1] = v.y; Wt[jj][k4+2] = v.z; Wt[jj][k4+3] = v.w;
    }
  }
  __syncthreads();
  const int jg = tid & 31, bg = tid >> 5;
  const int bl = bg << 2;
  float acc[4][4] = {};
  #pragma unroll 4
  for (int k = 0; k < 128; k += 2) {
    float2 xv[4], wv[4];
    #pragma unroll
    for (int b2 = 0; b2 < 4; b2++)
      xv[b2] = *reinterpret_cast<const float2*>(&Xs[bl + b2][k]);
    #pragma unroll
    for (int jj = 0; jj < 4; jj++)
      wv[jj] = *reinterpret_cast<const float2*>(&Wt[jg + (jj << 5)][k]);
    #pragma unroll
    for (int jj = 0; jj < 4; jj++)
      #pragma unroll
      for (int b2 = 0; b2 < 4; b2++)
        acc[jj][b2] += wv[jj].x * xv[b2].x + wv[jj].y * xv[b2].y;
  }
  #pragma unroll
  for (int jj = 0; jj < 4; jj++)
    #pragma unroll
    for (int b2 = 0; b2 < 4; b2++)
      partial[((size_t)kcb*Bz + (bl + b2))*G4D + j0 + jg + (jj << 5)] = acc[jj][b2];
}

__global__ __launch_bounds__(512) void k_fused(
    const float* __restrict__ partial, const float* __restrict__ b_ih,
    const float* __restrict__ b_hh,
    float* __restrict__ h, float* __restrict__ c,
    const float* __restrict__ W_g, const float* __restrict__ b_g,
    const float* __restrict__ memory, const int* __restrict__ lens,
    float* __restrict__ ctxs, float* __restrict__ ctx_out,
    float* __restrict__ align_out, float* __restrict__ term_out,
    int t, int final_, int nkc)
{
  const int b = blockIdx.x, tid = threadIdx.x;
  __shared__ float4 gs4[G4D/4];
  __shared__ float hsb[Dz];
  __shared__ float phis[3*Mz];
  __shared__ float prm[3*Mz];
  __shared__ float wsm[Lz];
  __shared__ int   rng[2];
  float* gs = (float*)gs4;
  {
    int j = 4*tid;
    float4 bi = *reinterpret_cast<const float4*>(&b_ih[j]);
    float4 bh = *reinterpret_cast<const float4*>(&b_hh[j]);
    float4 s = make_float4(bi.x+bh.x, bi.y+bh.y, bi.z+bh.z, bi.w+bh.w);
    const float4* pp = reinterpret_cast<const float4*>(partial) + (size_t)b*(G4D/4) + tid;
    for (int kcb = 0; kcb < nkc; kcb++) {
      float4 p = pp[(size_t)kcb*Bz*(G4D/4)];
      s.x += p.x; s.y += p.y; s.z += p.z; s.w += p.w;
    }
    gs4[tid] = s;
  }
  __syncthreads();
  {
    const int d = tid;
    float ig = 1.0f / (1.0f + expf(-gs[d]));
    float fg = 1.0f / (1.0f + expf(-gs[Dz + d]));
    float gg = tanhf(gs[2*Dz + d]);
    float og = 1.0f / (1.0f + expf(-gs[3*Dz + d]));
    float cn = fg * c[b*Dz + d] + ig * gg;
    float hn = og * tanhf(cn);
    c[b*Dz + d] = cn;
    h[b*Dz + d] = hn;
    hsb[d] = hn;
  }
  __syncthreads();
  if (tid < 16*3*Mz) {
    int m = tid >> 4, l16 = tid & 15;
    float s = 0.f;
    #pragma unroll 4
    for (int k = l16; k < Dz; k += 16) s += W_g[m*Dz + k] * hsb[k];
    s += __shfl_xor(s, 1);
    s += __shfl_xor(s, 2);
    s += __shfl_xor(s, 4);
    s += __shfl_xor(s, 8);
    if (l16 == 0) phis[m] = s + b_g[m];
  }
  __syncthreads();
  if (tid == 0) {
    float mx = -1e30f;
    #pragma unroll
    for (int m = 0; m < Mz; m++) mx = fmaxf(mx, phis[2*Mz + m]);
    float ae[Mz], ssum = 0.f;
    #pragma unroll
    for (int m = 0; m < Mz; m++) { ae[m] = expf(phis[2*Mz + m] - mx); ssum += ae[m]; }
    float lo = 1e30f, hi = -1e30f;
    #pragma unroll
    for (int m = 0; m < Mz; m++) {
      float ks = expf(phis[m]);
      float be = expf(phis[Mz + m]);
      prm[m]        = ks;
      prm[Mz + m]   = expf(-phis[Mz + m]);
      prm[2*Mz + m] = ae[m] / ssum;
      lo = fminf(lo, ks - 0.5f - 25.f*be);
      hi = fmaxf(hi, ks + 0.5f + 25.f*be);
    }
    int llo = lo > 0.f ? (int)floorf(lo) : 0;
    if (llo > Lz) llo = Lz;
    int lhi = hi < (float)Lz ? (int)ceilf(hi) + 1 : Lz;
    if (lhi > Lz) lhi = Lz;
    rng[0] = llo; rng[1] = lhi;
  }
  __syncthreads();
  const int llo = rng[0], lhi = rng[1];
  for (int l = llo + tid; l < lhi; l += 512) {
    float u = (float)l;
    float t1 = 0.f, t0 = 0.f;
    #pragma unroll
    for (int m = 0; m < Mz; m++) {
      float ks = prm[m], ib = prm[Mz + m], al = prm[2*Mz + m];
      t1 += al * fsig((u + 0.5f - ks) * ib);
      t0 += al * fsig((u - 0.5f - ks) * ib);
    }
    float w = t1 - t0;
    wsm[l] = w;
    align_out[((size_t)b*Tz + t)*Lz + l] = w;
  }
  __syncthreads();
  {
    const float* mb = memory + (size_t)b*Lz*Dz + tid;
    float acc = 0.f;
    #pragma unroll 4
    for (int l = llo; l < lhi; l++)
      acc += wsm[l] * mb[(size_t)l*Dz];
    ctxs[b*Dz + tid] = acc;
    if (final_) ctx_out[b*Dz + tid] = acc;
  }
  if (final_ && tid == 0) {
    float u = (float)(lens[b] - 1);
    float t1 = 0.f;
    #pragma unroll
    for (int m = 0; m < Mz; m++)
      t1 += prm[2*Mz + m] * fsig((u + 0.5f - prm[m]) * prm[Mz + m]);
    term_out[b] = 1.0f - t1;
  }
}

extern "C" void kernel_launch(void* const* d_in, const int* in_sizes, int n_in,
                              void* d_out, int out_size, void* d_ws, size_t ws_size,
                              hipStream_t stream)
{
  (void)in_sizes; (void)n_in; (void)out_size;
  const float* x    = (const float*)d_in[0];
  const float* mem  = (const float*)d_in[1];
  const int*   lens = (const int*)d_in[2];
  const float* W_ih = (const float*)d_in[3];
  const float* W_hh = (const float*)d_in[4];
  const float* b_ih = (const float*)d_in[5];
  const float* b_hh = (const float*)d_in[6];
  const float* W_g  = (const float*)d_in[7];
  const float* b_g  = (const float*)d_in[8];

  float* out = (float*)d_out;
  float* ctx_out   = out;                                  // [B,1,D]
  float* align_out = out + Bz*Dz;                          // [B,T,L]
  float* term_out  = out + Bz*Dz + (size_t)Bz*Tz*Lz;       // [B,1]

  const size_t needP = ((size_t)OFF_XW + (size_t)Bz*Tz*G4D) * sizeof(float);

  hipMemsetAsync(align_out, 0, (size_t)Bz*Tz*Lz*sizeof(float), stream);

  if (ws_size >= needP) {
    int* ip    = (int*)d_ws;
    int* fG    = ip + OFF_FG;
    int* fH    = ip + OFF_FH;
    int* fC    = ip + OFF_FC;
    u32* statc = (u32*)(ip + OFF_SC);
    u32* stath = (u32*)(ip + OFF_SH);
    u32* part  = (u32*)(ip + OFF_PART);
    float* xw  = (float*)(ip + OFF_XW);

    // zero flags + stat (initial state = 0); part fully overwritten each step
    hipMemsetAsync(d_ws, 0, (size_t)OFF_PART * sizeof(int), stream);
    k_pre<<<dim3((Bz*Tz)/PM, G4D/PN), 256, 0, stream>>>(x, W_ih, b_ih, b_hh, xw);
    k_persist<<<NBLK, 512, 0, stream>>>(mem, lens, W_ih, W_hh, W_g, b_g, xw,
                                        statc, stath, part, fG, fH, fC,
                                        ctx_out, align_out, term_out);
  } else {
    float* wsf     = (float*)d_ws;
    float* h       = wsf;
    float* c       = h + Bz*Dz;
    float* ctxs    = c + Bz*Dz;
    float* partial = ctxs + Bz*Dz;               // [12][B][4D]
    hipMemsetAsync(d_ws, 0, (size_t)(3*Bz*Dz)*sizeof(float), stream);
    for (int t = 0; t < Tz; t++) {
      k_gemm<<<dim3(G4D/128, 12), 256, 0, stream>>>(x, ctxs, h, W_ih, W_hh, partial, t);
      k_fused<<<Bz, 512, 0, stream>>>(partial, b_ih, b_hh, h, c, W_g, b_g,
                                      mem, lens, ctxs, ctx_out, align_out, term_out,
                                      t, t == Tz-1, 12);
    }
  }
}

// Round 14
// 6628.410 us; speedup vs baseline: 1.1945x; 1.0250x over previous
//
#include <hip/hip_runtime.h>

#define Bz 32
#define Tz 512
#define Dz 512
#define Lz 1024
#define Mz 10
#define G4D 2048
#define FP 32                // ints per flag slot (128B)
#define NBLKA 16             // A-blocks: 128 j x K=512 (W_hh) each
#define NBLK  48             // + 32 B-blocks
// ws int-region offsets
#define OFF_FG   0                        // [16*FP] = 512
#define OFF_FH   512                      // [32*FP] = 1024
#define OFF_SH   1536                     // stat_h[32][256] u32
#define OFF_PART 9728                     // part[32][1024] u32 (f16 pairs)
#define OFF_M2   42496                    // M2[32768][1024] u32 (f16 pairs) = 128MB
#define OFF_XW   33596928                 // xw[16384][1024] u32 (f16 pairs) = 64MB
#define NEED_I   50374144                 // total ints
// k_pre tiles
#define PM 128
#define PN 128
#define PK 32

typedef unsigned long long u64;
typedef unsigned u32;
typedef _Float16 f16x8 __attribute__((ext_vector_type(8)));
typedef float f32x4 __attribute__((ext_vector_type(4)));
typedef _Float16 half2_t __attribute__((ext_vector_type(2)));

__device__ __forceinline__ float fsig(float x) { return 1.0f / (1.0f + __expf(-x)); }
__device__ __forceinline__ int ld_rlx(const int* p) {
  return __hip_atomic_load(p, __ATOMIC_RELAXED, __HIP_MEMORY_SCOPE_AGENT);
}
__device__ __forceinline__ void st_rlx(int* p, int v) {
  __hip_atomic_store(p, v, __ATOMIC_RELAXED, __HIP_MEMORY_SCOPE_AGENT);
}
__device__ __forceinline__ void st_rlxu(u32* p, u32 v) {
  __hip_atomic_store(p, v, __ATOMIC_RELAXED, __HIP_MEMORY_SCOPE_AGENT);
}
__device__ __forceinline__ u64 ld_rlx64(const u64* p) {
  return __hip_atomic_load(p, __ATOMIC_RELAXED, __HIP_MEMORY_SCOPE_AGENT);
}
__device__ __forceinline__ u32 pack16(float a, float b) {
  unsigned short la = __builtin_bit_cast(unsigned short, (_Float16)a);
  unsigned short lb = __builtin_bit_cast(unsigned short, (_Float16)b);
  return (u32)la | ((u32)lb << 16);
}
__device__ __forceinline__ float lo16(u32 v) {
  return (float)__builtin_bit_cast(half2_t, v)[0];
}
__device__ __forceinline__ float hi16(u32 v) {
  return (float)__builtin_bit_cast(half2_t, v)[1];
}
#define VWAIT() asm volatile("s_waitcnt vmcnt(0)" ::: "memory")

// ---------------- K0 (once): xw_f16[bt][j] = x[bt,:].W_ih[j,0:512] + b_ih[j] + b_hh[j] ----------------
__global__ __launch_bounds__(256) void k_pre(
    const float* __restrict__ x, const float* __restrict__ W_ih,
    const float* __restrict__ b_ih, const float* __restrict__ b_hh,
    u32* __restrict__ xwu)
{
  __shared__ float As[PM][PK+1];
  __shared__ float Bs[PN][PK+1];
  const int m0 = blockIdx.x*PM, n0 = blockIdx.y*PN;
  const int tid = threadIdx.x;
  const int mg = tid >> 4, ng = tid & 15;
  float acc[8][8] = {};
  for (int k0 = 0; k0 < Dz; k0 += PK) {
    for (int i = tid; i < PM*(PK/4); i += 256) {
      int row = i >> 3, c4 = (i & 7) << 2;
      float4 v = *reinterpret_cast<const float4*>(&x[(size_t)(m0+row)*Dz + k0 + c4]);
      As[row][c4] = v.x; As[row][c4+1] = v.y; As[row][c4+2] = v.z; As[row][c4+3] = v.w;
    }
    for (int i = tid; i < PN*(PK/4); i += 256) {
      int row = i >> 3, c4 = (i & 7) << 2;
      float4 v = *reinterpret_cast<const float4*>(&W_ih[(size_t)(n0+row)*(2*Dz) + k0 + c4]);
      Bs[row][c4] = v.x; Bs[row][c4+1] = v.y; Bs[row][c4+2] = v.z; Bs[row][c4+3] = v.w;
    }
    __syncthreads();
    #pragma unroll 8
    for (int k = 0; k < PK; k++) {
      float a8[8], b8[8];
      #pragma unroll
      for (int r = 0; r < 8; r++) a8[r] = As[mg*8+r][k];
      #pragma unroll
      for (int s = 0; s < 8; s++) b8[s] = Bs[ng*8+s][k];
      #pragma unroll
      for (int r = 0; r < 8; r++)
        #pragma unroll
        for (int s = 0; s < 8; s++) acc[r][s] += a8[r]*b8[s];
    }
    __syncthreads();
  }
  const int nb = n0 + ng*8;
  #pragma unroll
  for (int r = 0; r < 8; r++) {
    int m = m0 + mg*8 + r;
    #pragma unroll
    for (int s2 = 0; s2 < 4; s2++) {
      int n = nb + 2*s2;
      xwu[(size_t)m*1024 + (n >> 1)] =
          pack16(acc[r][2*s2]   + b_ih[n]   + b_hh[n],
                 acc[r][2*s2+1] + b_ih[n+1] + b_hh[n+1]);
    }
  }
}

// ---------------- K1 (once): M2[m][j] = memory[m,:] . W_ic[j,:]  (f16 pairs) ----------------
// m = b*1024 + l (32768 rows, K=512), W_ic = W_ih[:, 512:1024]. MFMA 16x16x32.
__global__ __launch_bounds__(512) void k_m2(
    const float* __restrict__ memory, const float* __restrict__ W_ih,
    u32* __restrict__ M2u)
{
  __shared__ __align__(16) u32 smem[149760/4];
  u32* Bs = smem;              // [128][260] swizzled
  u32* As = smem + 33280;      // [16][260]
  const int tid = threadIdx.x;
  const int n0 = blockIdx.x * 128, mc = blockIdx.y;
  // stage B (W_ic rows n0..n0+127) once
  for (int i = tid; i < 128*256; i += 512) {
    int jl = i >> 8, ku = i & 255;
    float2 wv = *reinterpret_cast<const float2*>(&W_ih[(size_t)(n0+jl)*(2*Dz) + 512 + 2*ku]);
    Bs[jl*260 + (ku ^ ((jl & 7) << 2))] = pack16(wv.x, wv.y);
  }
  __syncthreads();
  const int w = tid >> 6, lane = tid & 63;
  const int fr = lane & 15, kq = (lane >> 4) << 2;
  const int frsw = (fr & 7) << 2;
  for (int mt = 0; mt < 128; ++mt) {
    const int m0 = mc*2048 + mt*16;
    for (int i = tid; i < 16*256; i += 512) {
      int r = i >> 8, ku = i & 255;
      float2 mv = *reinterpret_cast<const float2*>(&memory[(size_t)(m0+r)*Dz + 2*ku]);
      As[r*260 + (ku ^ ((r & 7) << 2))] = pack16(mv.x, mv.y);
    }
    __syncthreads();
    f32x4 acc = {0.f, 0.f, 0.f, 0.f};
    #pragma unroll
    for (int ks = 0; ks < 16; ++ks) {
      int col = (kq + ks*16) ^ frsw;
      f16x8 av = *reinterpret_cast<const f16x8*>(As + fr*260 + col);
      f16x8 bv = *reinterpret_cast<const f16x8*>(Bs + (w*16 + fr)*260 + col);
      acc = __builtin_amdgcn_mfma_f32_16x16x32_f16(av, bv, acc, 0, 0, 0);
    }
    #pragma unroll
    for (int i = 0; i < 4; ++i) {
      float oth = __shfl_xor(acc[i], 1);
      if (!(lane & 1)) {
        int m = m0 + ((lane >> 4) << 2) + i;
        int j = n0 + w*16 + fr;
        M2u[(size_t)m*1024 + (j >> 1)] = pack16(acc[i], oth);
      }
    }
    __syncthreads();
  }
}

// ---------------- Persistent kernel: h-only MFMA GEMM + local gctx einsum ----------------
__global__ __launch_bounds__(512, 1) void k_persist(
    const float* __restrict__ memory, const int* __restrict__ lens,
    const float* __restrict__ W_hh, const float* __restrict__ W_g,
    const float* __restrict__ b_g,
    const u32* __restrict__ xwu, const u32* __restrict__ M2u,
    u32* __restrict__ stat_h, u32* __restrict__ part,
    int* __restrict__ fG, int* __restrict__ fH,
    float* __restrict__ ctx_out, float* __restrict__ align_out,
    float* __restrict__ term_out)
{
  const int blk = blockIdx.x, tid = threadIdx.x;
  __shared__ __align__(16) char smem[149760];
  __shared__ float phis[3*Mz], prm[3*Mz], lom[Mz], him[Mz];
  __shared__ int rng[2];

  if (blk < NBLKA) {
    // ================= A role: gates_h partials for 128 j, all batches =================
    const int j0 = blk * 128;
    u32* Wl = (u32*)smem;                 // [128][260] swizzled f16 pairs
    u32* xs = (u32*)(smem + 133120);      // [16][260]

    for (int i = tid; i < 128*256; i += 512) {
      int jl = i >> 8, ku = i & 255;
      float2 wv = *reinterpret_cast<const float2*>(&W_hh[(size_t)(j0+jl)*Dz + 2*ku]);
      Wl[jl*260 + (ku ^ ((jl & 7) << 2))] = pack16(wv.x, wv.y);
    }

    const int w = tid >> 6, lane = tid & 63;
    const int fr = lane & 15, kq = (lane >> 4) << 2;
    const int frsw = (fr & 7) << 2;

    for (int t = 0; t < Tz; ++t) {
      if (t > 0 && tid < Bz) {
        while (ld_rlx(&fH[tid*FP]) < t) __builtin_amdgcn_s_sleep(1);
      }
      __syncthreads();

      #pragma unroll
      for (int hh = 0; hh < 2; ++hh) {
        // stage 16 batches' h (b-major stat_h, u64 with write-side swizzle)
        #pragma unroll
        for (int q = 0; q < 4; ++q) {
          int flat = (q << 9) + tid;
          int bb = flat >> 7, ku2 = flat & 127;
          u64 v = ld_rlx64(reinterpret_cast<const u64*>(stat_h) + (size_t)(hh*16 + bb)*128 + ku2);
          *reinterpret_cast<u64*>(&xs[bb*260 + ((2*ku2) ^ ((bb & 7) << 2))]) = v;
        }
        __syncthreads();

        f32x4 acc = {0.f, 0.f, 0.f, 0.f};
        #pragma unroll
        for (int ks = 0; ks < 16; ++ks) {
          int col = (kq + ks*16) ^ frsw;
          f16x8 av = *reinterpret_cast<const f16x8*>(xs + fr*260 + col);
          f16x8 bv = *reinterpret_cast<const f16x8*>(Wl + (w*16 + fr)*260 + col);
          acc = __builtin_amdgcn_mfma_f32_16x16x32_f16(av, bv, acc, 0, 0, 0);
        }
        #pragma unroll
        for (int i = 0; i < 4; ++i) {
          float oth = __shfl_xor(acc[i], 1);
          if (!(lane & 1)) {
            int bg = hh*16 + ((lane >> 4) << 2) + i;
            int jc = j0 + w*16 + fr;
            st_rlxu(&part[bg*1024 + (jc >> 1)], pack16(acc[i], oth));
          }
        }
        __syncthreads();
      }
      VWAIT();
      __syncthreads();
      if (tid == 0) st_rlx(&fG[blk*FP], t+1);
    }
    return;
  }

  // ================= B role =================
  const int b = blk - NBLKA;
  float* gs   = reinterpret_cast<float*>(smem);           // 2048 f
  float* gctx = reinterpret_cast<float*>(smem + 8192);    // 2048 f
  float* wsm  = reinterpret_cast<float*>(smem + 16384);   // 1024 f
  float* hs   = reinterpret_cast<float*>(smem + 20480);   // 512 f
  float* cs   = reinterpret_cast<float*>(smem + 22528);   // 512 f
  float* part4 = gs;                                      // final-ctx partials overlay gs

  cs[tid] = 0.f;
  #pragma unroll
  for (int q = 0; q < 4; ++q) gctx[(q << 9) + tid] = 0.f;   // ctx(-1) = 0
  __syncthreads();

  for (int t = 0; t < Tz; ++t) {
    // prefetch xw row (u64 = 4 f16 gates j=4tid..4tid+3)
    u64 xv = *(reinterpret_cast<const u64*>(xwu) + ((size_t)(b*Tz + t) << 9) + tid);

    if (tid < NBLKA) {
      while (ld_rlx(&fG[tid*FP]) < t+1) __builtin_amdgcn_s_sleep(1);
    }
    __syncthreads();

    // gates = xw + h-part + gctx ; thread owns j = 4tid..4tid+3
    {
      u64 pv = ld_rlx64(reinterpret_cast<const u64*>(part) + (size_t)b*512 + tid);
      u32 x0 = (u32)xv, x1 = (u32)(xv >> 32);
      u32 p0 = (u32)pv, p1 = (u32)(pv >> 32);
      float g0 = lo16(x0) + lo16(p0) + gctx[4*tid];
      float g1 = hi16(x0) + hi16(p0) + gctx[4*tid+1];
      float g2 = lo16(x1) + lo16(p1) + gctx[4*tid+2];
      float g3 = hi16(x1) + hi16(p1) + gctx[4*tid+3];
      *reinterpret_cast<float4*>(&gs[4*tid]) = make_float4(g0, g1, g2, g3);
    }
    __syncthreads();

    // LSTM pointwise (d = tid); gate order i,f,g,o
    {
      const int d = tid;
      float ig = 1.0f/(1.0f+expf(-gs[d]));
      float fg = 1.0f/(1.0f+expf(-gs[Dz+d]));
      float gg = tanhf(gs[2*Dz+d]);
      float og = 1.0f/(1.0f+expf(-gs[3*Dz+d]));
      float cn = fg*cs[d] + ig*gg;
      float hn = og*tanhf(cn);
      cs[d] = cn; hs[d] = hn;
    }
    __syncthreads();
    if (tid < 256)
      st_rlxu(&stat_h[b*256 + tid], pack16(hs[2*tid], hs[2*tid+1]));
    VWAIT();
    __syncthreads();
    if (tid == 0) st_rlx(&fH[b*FP], t+1);   // release A-blocks NOW

    // phi[m] = hs . W_g[m,:] + b_g[m]  (16 lanes/m)
    if (tid < 16*3*Mz) {
      int m = tid >> 4, l16 = tid & 15;
      const float4* wr = reinterpret_cast<const float4*>(W_g + m*Dz);
      const float4* hr = reinterpret_cast<const float4*>(hs);
      float s = 0.f;
      #pragma unroll
      for (int i = 0; i < 8; i++) {
        float4 wv = wr[l16 + (i<<4)];
        float4 hv = hr[l16 + (i<<4)];
        s += wv.x*hv.x + wv.y*hv.y + wv.z*hv.z + wv.w*hv.w;
      }
      s += __shfl_xor(s, 1);
      s += __shfl_xor(s, 2);
      s += __shfl_xor(s, 4);
      s += __shfl_xor(s, 8);
      if (l16 == 0) phis[m] = s + b_g[m];
    }
    __syncthreads();

    // GMM params + active range
    if (tid < Mz) {
      float ks = expf(phis[tid]);
      float be = expf(phis[Mz + tid]);
      prm[tid]      = ks;
      prm[Mz + tid] = expf(-phis[Mz + tid]);   // 1/beta
      lom[tid] = ks - 0.5f - 25.f*be;          // sig(-25) < fp32 visibility
      him[tid] = ks + 0.5f + 25.f*be;
    }
    __syncthreads();
    if (tid == 0) {
      float mx = -1e30f;
      #pragma unroll
      for (int m = 0; m < Mz; m++) mx = fmaxf(mx, phis[2*Mz + m]);
      float ae[Mz], ssum = 0.f;
      #pragma unroll
      for (int m = 0; m < Mz; m++) { ae[m] = expf(phis[2*Mz + m] - mx); ssum += ae[m]; }
      float lo = 1e30f, hi = -1e30f;
      #pragma unroll
      for (int m = 0; m < Mz; m++) {
        prm[2*Mz + m] = ae[m] / ssum;
        lo = fminf(lo, lom[m]); hi = fmaxf(hi, him[m]);
      }
      int llo = lo > 0.f ? (int)floorf(lo) : 0;
      if (llo > Lz) llo = Lz;
      int lhi = hi < (float)Lz ? (int)ceilf(hi) + 1 : Lz;
      if (lhi > Lz) lhi = Lz;
      rng[0] = llo; rng[1] = lhi;
    }
    __syncthreads();
    const int llo = rng[0], lhi = rng[1];

    // w on active range
    for (int l = llo + tid; l < lhi; l += 512) {
      float u = (float)l;
      float t1 = 0.f, t0 = 0.f;
      #pragma unroll
      for (int m = 0; m < Mz; m++) {
        float ks = prm[m], ib = prm[Mz + m], al = prm[2*Mz + m];
        t1 += al * fsig((u + 0.5f - ks) * ib);
        t0 += al * fsig((u - 0.5f - ks) * ib);
      }
      wsm[l] = t1 - t0;
    }
    __syncthreads();

    if (t < Tz-1) {
      // gctx(t+1)[j] = sum_l w_l * M2[b*1024+l][j]  (thread owns j=4tid..4tid+3)
      float a0 = 0.f, a1 = 0.f, a2 = 0.f, a3 = 0.f;
      const u64* m2r = reinterpret_cast<const u64*>(M2u) + ((size_t)(b << 10) << 9) + tid;
      for (int l = llo; l < lhi; ++l) {
        float wl = wsm[l];
        u64 v = m2r[(size_t)l << 9];
        u32 v0 = (u32)v, v1 = (u32)(v >> 32);
        a0 = fmaf(wl, lo16(v0), a0);
        a1 = fmaf(wl, hi16(v0), a1);
        a2 = fmaf(wl, lo16(v1), a2);
        a3 = fmaf(wl, hi16(v1), a3);
      }
      *reinterpret_cast<float4*>(&gctx[4*tid]) = make_float4(a0, a1, a2, a3);
    } else {
      // final step: ctx_out = sum_l w_l * memory[b,l,:]
      __syncthreads();   // gs (LSTM inputs) dead -> part4 overlay safe
      {
        const int grp = tid >> 7, d0 = (tid & 127) << 2;
        const float* mb = memory + (size_t)b*Lz*Dz + d0;
        float4 a = make_float4(0.f, 0.f, 0.f, 0.f);
        for (int l = llo + grp; l < lhi; l += 4) {
          float wl = wsm[l];
          float4 m0 = *reinterpret_cast<const float4*>(&mb[(size_t)l*Dz]);
          a.x = fmaf(wl, m0.x, a.x); a.y = fmaf(wl, m0.y, a.y);
          a.z = fmaf(wl, m0.z, a.z); a.w = fmaf(wl, m0.w, a.w);
        }
        *reinterpret_cast<float4*>(&part4[grp*512 + d0]) = a;
      }
      __syncthreads();
      ctx_out[b*Dz + tid] = part4[tid] + part4[512 + tid] + part4[1024 + tid] + part4[1536 + tid];
      if (tid == 0) {
        float u = (float)(lens[b] - 1);
        float t1 = 0.f;
        #pragma unroll
        for (int m = 0; m < Mz; m++)
          t1 += prm[2*Mz + m] * fsig((u + 0.5f - prm[m]) * prm[Mz + m]);
        term_out[b] = 1.0f - t1;
      }
    }

    // off critical path: alignment row
    for (int l = llo + tid; l < lhi; l += 512)
      align_out[((size_t)b*Tz + t)*Lz + l] = wsm[l];
  }
}

// ================= fallback (small ws): two-kernel loop path =================
__global__ __launch_bounds__(256) void k_gemm(
    const float* __restrict__ x_all, const float* __restrict__ ctxs,
    const float* __restrict__ h, const float* __restrict__ W_ih,
    const float* __restrict__ W_hh, float* __restrict__ partial, int t)
{
  __shared__ float Xs[Bz][130];
  __shared__ float Wt[128][130];
  const int jt = blockIdx.x, kcb = blockIdx.y;
  const int j0 = jt*128, k0 = kcb*128;
  const int tid = threadIdx.x;
  for (int i = tid; i < Bz*128; i += 256) {
    int bb = i >> 7, kk = i & 127;
    int k = k0 + kk;
    float v;
    if (k < Dz)        v = x_all[((size_t)bb*Tz + t)*Dz + k];
    else if (k < 2*Dz) v = ctxs[bb*Dz + (k - Dz)];
    else               v = h[bb*Dz + (k - 2*Dz)];
    Xs[bb][kk] = v;
  }
  {
    const float* Wsrc; int ldw, col0;
    if (k0 < 2*Dz) { Wsrc = W_ih; ldw = 2*Dz; col0 = k0; }
    else           { Wsrc = W_hh; ldw = Dz;   col0 = k0 - 2*Dz; }
    for (int i = tid; i < 128*32; i += 256) {
      int jj = i >> 5, k4 = (i & 31) << 2;
      float4 v = *reinterpret_cast<const float4*>(&Wsrc[(size_t)(j0 + jj)*ldw + col0 + k4]);
      Wt[jj][k4] = v.x; Wt[jj][k4+1] = v.y; Wt[jj][k4+2] = v.z; Wt[jj][k4+3] = v.w;
    }
  }
  __syncthreads();
  const int jg = tid & 31, bg = tid >> 5;
  const int bl = bg << 2;
  float acc[4][4] = {};
  #pragma unroll 4
  for (int k = 0; k < 128; k += 2) {
    float2 xv[4], wv[4];
    #pragma unroll
    for (int b2 = 0; b2 < 4; b2++)
      xv[b2] = *reinterpret_cast<const float2*>(&Xs[bl + b2][k]);
    #pragma unroll
    for (int jj = 0; jj < 4; jj++)
      wv[jj] = *reinterpret_cast<const float2*>(&Wt[jg + (jj << 5)][k]);
    #pragma unroll
    for (int jj = 0; jj < 4; jj++)
      #pragma unroll
      for (int b2 = 0; b2 < 4; b2++)
        acc[jj][b2] += wv[jj].x * xv[b2].x + wv[jj].y * xv[b2].y;
  }
  #pragma unroll
  for (int jj = 0; jj < 4; jj++)
    #pragma unroll
    for (int b2 = 0; b2 < 4; b2++)
      partial[((size_t)kcb*Bz + (bl + b2))*G4D + j0 + jg + (jj << 5)] = acc[jj][b2];
}

__global__ __launch_bounds__(512) void k_fused(
    const float* __restrict__ partial, const float* __restrict__ b_ih,
    const float* __restrict__ b_hh,
    float* __restrict__ h, float* __restrict__ c,
    const float* __restrict__ W_g, const float* __restrict__ b_g,
    const float* __restrict__ memory, const int* __restrict__ lens,
    float* __restrict__ ctxs, float* __restrict__ ctx_out,
    float* __restrict__ align_out, float* __restrict__ term_out,
    int t, int final_, int nkc)
{
  const int b = blockIdx.x, tid = threadIdx.x;
  __shared__ float4 gs4[G4D/4];
  __shared__ float hsb[Dz];
  __shared__ float phis[3*Mz];
  __shared__ float prm[3*Mz];
  __shared__ float wsm[Lz];
  __shared__ int   rng[2];
  float* gs = (float*)gs4;
  {
    int j = 4*tid;
    float4 bi = *reinterpret_cast<const float4*>(&b_ih[j]);
    float4 bh = *reinterpret_cast<const float4*>(&b_hh[j]);
    float4 s = make_float4(bi.x+bh.x, bi.y+bh.y, bi.z+bh.z, bi.w+bh.w);
    const float4* pp = reinterpret_cast<const float4*>(partial) + (size_t)b*(G4D/4) + tid;
    for (int kcb = 0; kcb < nkc; kcb++) {
      float4 p = pp[(size_t)kcb*Bz*(G4D/4)];
      s.x += p.x; s.y += p.y; s.z += p.z; s.w += p.w;
    }
    gs4[tid] = s;
  }
  __syncthreads();
  {
    const int d = tid;
    float ig = 1.0f / (1.0f + expf(-gs[d]));
    float fg = 1.0f / (1.0f + expf(-gs[Dz + d]));
    float gg = tanhf(gs[2*Dz + d]);
    float og = 1.0f / (1.0f + expf(-gs[3*Dz + d]));
    float cn = fg * c[b*Dz + d] + ig * gg;
    float hn = og * tanhf(cn);
    c[b*Dz + d] = cn;
    h[b*Dz + d] = hn;
    hsb[d] = hn;
  }
  __syncthreads();
  if (tid < 16*3*Mz) {
    int m = tid >> 4, l16 = tid & 15;
    float s = 0.f;
    #pragma unroll 4
    for (int k = l16; k < Dz; k += 16) s += W_g[m*Dz + k] * hsb[k];
    s += __shfl_xor(s, 1);
    s += __shfl_xor(s, 2);
    s += __shfl_xor(s, 4);
    s += __shfl_xor(s, 8);
    if (l16 == 0) phis[m] = s + b_g[m];
  }
  __syncthreads();
  if (tid == 0) {
    float mx = -1e30f;
    #pragma unroll
    for (int m = 0; m < Mz; m++) mx = fmaxf(mx, phis[2*Mz + m]);
    float ae[Mz], ssum = 0.f;
    #pragma unroll
    for (int m = 0; m < Mz; m++) { ae[m] = expf(phis[2*Mz + m] - mx); ssum += ae[m]; }
    float lo = 1e30f, hi = -1e30f;
    #pragma unroll
    for (int m = 0; m < Mz; m++) {
      float ks = expf(phis[m]);
      float be = expf(phis[Mz + m]);
      prm[m]        = ks;
      prm[Mz + m]   = expf(-phis[Mz + m]);
      prm[2*Mz + m] = ae[m] / ssum;
      lo = fminf(lo, ks - 0.5f - 25.f*be);
      hi = fmaxf(hi, ks + 0.5f + 25.f*be);
    }
    int llo = lo > 0.f ? (int)floorf(lo) : 0;
    if (llo > Lz) llo = Lz;
    int lhi = hi < (float)Lz ? (int)ceilf(hi) + 1 : Lz;
    if (lhi > Lz) lhi = Lz;
    rng[0] = llo; rng[1] = lhi;
  }
  __syncthreads();
  const int llo = rng[0], lhi = rng[1];
  for (int l = llo + tid; l < lhi; l += 512) {
    float u = (float)l;
    float t1 = 0.f, t0 = 0.f;
    #pragma unroll
    for (int m = 0; m < Mz; m++) {
      float ks = prm[m], ib = prm[Mz + m], al = prm[2*Mz + m];
      t1 += al * fsig((u + 0.5f - ks) * ib);
      t0 += al * fsig((u - 0.5f - ks) * ib);
    }
    float w = t1 - t0;
    wsm[l] = w;
    align_out[((size_t)b*Tz + t)*Lz + l] = w;
  }
  __syncthreads();
  {
    const float* mb = memory + (size_t)b*Lz*Dz + tid;
    float acc = 0.f;
    #pragma unroll 4
    for (int l = llo; l < lhi; l++)
      acc += wsm[l] * mb[(size_t)l*Dz];
    ctxs[b*Dz + tid] = acc;
    if (final_) ctx_out[b*Dz + tid] = acc;
  }
  if (final_ && tid == 0) {
    float u = (float)(lens[b] - 1);
    float t1 = 0.f;
    #pragma unroll
    for (int m = 0; m < Mz; m++)
      t1 += prm[2*Mz + m] * fsig((u + 0.5f - prm[m]) * prm[Mz + m]);
    term_out[b] = 1.0f - t1;
  }
}

extern "C" void kernel_launch(void* const* d_in, const int* in_sizes, int n_in,
                              void* d_out, int out_size, void* d_ws, size_t ws_size,
                              hipStream_t stream)
{
  (void)in_sizes; (void)n_in; (void)out_size;
  const float* x    = (const float*)d_in[0];
  const float* mem  = (const float*)d_in[1];
  const int*   lens = (const int*)d_in[2];
  const float* W_ih = (const float*)d_in[3];
  const float* W_hh = (const float*)d_in[4];
  const float* b_ih = (const float*)d_in[5];
  const float* b_hh = (const float*)d_in[6];
  const float* W_g  = (const float*)d_in[7];
  const float* b_g  = (const float*)d_in[8];

  float* out = (float*)d_out;
  float* ctx_out   = out;                                  // [B,1,D]
  float* align_out = out + Bz*Dz;                          // [B,T,L]
  float* term_out  = out + Bz*Dz + (size_t)Bz*Tz*Lz;       // [B,1]

  const size_t needP = (size_t)NEED_I * sizeof(int);

  hipMemsetAsync(align_out, 0, (size_t)Bz*Tz*Lz*sizeof(float), stream);

  if (ws_size >= needP) {
    int* ip    = (int*)d_ws;
    int* fG    = ip + OFF_FG;
    int* fH    = ip + OFF_FH;
    u32* stath = (u32*)(ip + OFF_SH);
    u32* part  = (u32*)(ip + OFF_PART);
    u32* M2u   = (u32*)(ip + OFF_M2);
    u32* xwu   = (u32*)(ip + OFF_XW);

    hipMemsetAsync(d_ws, 0, (size_t)OFF_M2 * sizeof(int), stream);  // flags+stat_h(+part)
    k_pre<<<dim3((Bz*Tz)/PM, G4D/PN), 256, 0, stream>>>(x, W_ih, b_ih, b_hh, xwu);
    k_m2<<<dim3(16, 16), 512, 0, stream>>>(mem, W_ih, M2u);
    k_persist<<<NBLK, 512, 0, stream>>>(mem, lens, W_hh, W_g, b_g, xwu, M2u,
                                        stath, part, fG, fH,
                                        ctx_out, align_out, term_out);
  } else {
    float* wsf     = (float*)d_ws;
    float* h       = wsf;
    float* c       = h + Bz*Dz;
    float* ctxs    = c + Bz*Dz;
    float* partial = ctxs + Bz*Dz;               // [12][B][4D]
    hipMemsetAsync(d_ws, 0, (size_t)(3*Bz*Dz)*sizeof(float), stream);
    for (int t = 0; t < Tz; t++) {
      k_gemm<<<dim3(G4D/128, 12), 256, 0, stream>>>(x, ctxs, h, W_ih, W_hh, partial, t);
      k_fused<<<Bz, 512, 0, stream>>>(partial, b_ih, b_hh, h, c, W_g, b_g,
                                      mem, lens, ctxs, ctx_out, align_out, term_out,
                                      t, t == Tz-1, 12);
    }
  }
}